// Round 23
// baseline (224.543 us; speedup 1.0000x reference)
//
#include <hip/hip_runtime.h>
#include <math.h>

#define HEADS 8
#define DK 64
#define DMODEL 512
#define BATCH 2
#define SEQ 2048
#define BH (BATCH * HEADS)

using f32x4 = __attribute__((ext_vector_type(4))) float;
using s16x8 = __attribute__((ext_vector_type(8))) short;
using fp16x2 = __attribute__((ext_vector_type(2))) __fp16;  // cvt_pkrtz's type

union FragU {
  uint4 u;
  s16x8 s;
  unsigned short us[8];
};
union PkU {
  fp16x2 h;
  unsigned int u;
};

__device__ __forceinline__ unsigned short f32_to_bf16(float f) {
  unsigned int u = __float_as_uint(f);
  u += 0x7fffu + ((u >> 16) & 1u);
  return (unsigned short)(u >> 16);
}
__device__ __forceinline__ float bf16_to_f32(unsigned short h) {
  return __uint_as_float(((unsigned int)h) << 16);
}

// ---------------------------------------------------------------------------
// ALL FOUR W[512][512] f32 -> Wt hi/lo bf16 [n][k] in one launch.
// ---------------------------------------------------------------------------
__global__ __launch_bounds__(256) void wsplit4_kernel(
    const float* __restrict__ W0, const float* __restrict__ W1,
    const float* __restrict__ W2, const float* __restrict__ W3,
    unsigned short* __restrict__ WtHi4, unsigned short* __restrict__ WtLo4) {
  __shared__ float t[64][65];
  const int z = blockIdx.z;
  const float* W = (z == 0) ? W0 : (z == 1) ? W1 : (z == 2) ? W2 : W3;
  unsigned short* WtHi = WtHi4 + (size_t)z * (DMODEL * DMODEL);
  unsigned short* WtLo = WtLo4 + (size_t)z * (DMODEL * DMODEL);
  const int k0 = blockIdx.x * 64, n0 = blockIdx.y * 64;
  const int tid = threadIdx.x;
  const int r = tid >> 2, c = (tid & 3) * 16;
  #pragma unroll
  for (int e = 0; e < 4; ++e) {
    f32x4 v = *(const f32x4*)&W[(size_t)(k0 + r) * DMODEL + n0 + c + e * 4];
    #pragma unroll
    for (int j = 0; j < 4; ++j) t[r][c + e * 4 + j] = v[j];
  }
  __syncthreads();
  const int rn = tid >> 2, ck = (tid & 3) * 16;
  #pragma unroll
  for (int half = 0; half < 2; ++half) {
    FragU hi, lo;
    #pragma unroll
    for (int e = 0; e < 8; ++e) {
      float x = t[ck + half * 8 + e][rn];
      unsigned short h = f32_to_bf16(x);
      hi.us[e] = h;
      lo.us[e] = f32_to_bf16(x - bf16_to_f32(h));
    }
    const size_t o = (size_t)(n0 + rn) * DMODEL + k0 + ck + half * 8;
    *(uint4*)&WtHi[o] = hi.u;
    *(uint4*)&WtLo[o] = lo.u;
  }
}

// ---------------------------------------------------------------------------
// FUSED FRONT: Q/K/V projections (blocks 0..1535) + mask byte-pack (rest).
// ---------------------------------------------------------------------------
__global__ __launch_bounds__(256) void fused_front_kernel(
    const float* __restrict__ Xq, const float* __restrict__ Xk,
    const float* __restrict__ Xv, const unsigned short* __restrict__ WtHi4,
    const unsigned short* __restrict__ WtLo4, const float* __restrict__ bq,
    const float* __restrict__ bk, const float* __restrict__ bv,
    unsigned short* __restrict__ Qhi, unsigned short* __restrict__ Qlo,
    unsigned short* __restrict__ Khi, unsigned short* __restrict__ Vt,
    const int* __restrict__ mask, unsigned int* __restrict__ bits) {
  __shared__ unsigned short BsHi[64][72];
  __shared__ unsigned short BsLo[64][72];
  const int id = blockIdx.x;
  const int tid = threadIdx.x;

  if (id >= 1536) {
    const int row = id - 1536;  // 0..4095
    const int4* mrow = (const int4*)&mask[(size_t)row * SEQ + tid * 8];
    const int4 a = mrow[0];
    const int4 bb = mrow[1];
    unsigned int byte = 0;
    byte |= (a.x != 0) ? 1u : 0u;
    byte |= (a.y != 0) ? 2u : 0u;
    byte |= (a.z != 0) ? 4u : 0u;
    byte |= (a.w != 0) ? 8u : 0u;
    byte |= (bb.x != 0) ? 16u : 0u;
    byte |= (bb.y != 0) ? 32u : 0u;
    byte |= (bb.z != 0) ? 64u : 0u;
    byte |= (bb.w != 0) ? 128u : 0u;
    ((unsigned char*)bits)[(size_t)row * 256 + tid] = (unsigned char)byte;
    return;
  }

  const int z = id >> 9;
  const int rem = id & 511;
  const int m0 = (rem & 63) * 64;
  const int n0 = (rem >> 6) * 64;
  const float* X = (z == 0) ? Xq : (z == 1) ? Xk : Xv;
  const float* bias = (z == 0) ? bq : (z == 1) ? bk : bv;
  const unsigned short* WtHi = WtHi4 + (size_t)z * (DMODEL * DMODEL);
  const unsigned short* WtLo = WtLo4 + (size_t)z * (DMODEL * DMODEL);

  const int wv = tid >> 6, lane = tid & 63;
  const int lr = lane & 15, lg = lane >> 4;
  const int mw = m0 + wv * 16;

  f32x4 acc[4] = {};
  for (int k0 = 0; k0 < 512; k0 += 64) {
    FragU ah[2], al[2];
    #pragma unroll
    for (int dc = 0; dc < 2; ++dc) {
      const size_t xi = (size_t)(mw + lr) * DMODEL + k0 + dc * 32 + lg * 8;
      f32x4 x0 = *(const f32x4*)&X[xi];
      f32x4 x1 = *(const f32x4*)&X[xi + 4];
      #pragma unroll
      for (int t = 0; t < 4; ++t) {
        unsigned short h0 = f32_to_bf16(x0[t]);
        unsigned short h1 = f32_to_bf16(x1[t]);
        ah[dc].us[t] = h0;
        ah[dc].us[4 + t] = h1;
        al[dc].us[t] = f32_to_bf16(x0[t] - bf16_to_f32(h0));
        al[dc].us[4 + t] = f32_to_bf16(x1[t] - bf16_to_f32(h1));
      }
    }
    __syncthreads();
    #pragma unroll
    for (int e = 0; e < 2; ++e) {
      const int rr = (tid >> 3) + e * 32;
      const int cc = (tid & 7) * 8;
      *(uint4*)&BsHi[rr][cc] =
          *(const uint4*)&WtHi[(size_t)(n0 + rr) * DMODEL + k0 + cc];
      *(uint4*)&BsLo[rr][cc] =
          *(const uint4*)&WtLo[(size_t)(n0 + rr) * DMODEL + k0 + cc];
    }
    __syncthreads();
    #pragma unroll
    for (int jt = 0; jt < 4; ++jt) {
      #pragma unroll
      for (int dc = 0; dc < 2; ++dc) {
        FragU bh, bl;
        bh.u = *(const uint4*)&BsHi[jt * 16 + lr][dc * 32 + lg * 8];
        bl.u = *(const uint4*)&BsLo[jt * 16 + lr][dc * 32 + lg * 8];
        acc[jt] = __builtin_amdgcn_mfma_f32_16x16x32_bf16(ah[dc].s, bh.s, acc[jt], 0, 0, 0);
        acc[jt] = __builtin_amdgcn_mfma_f32_16x16x32_bf16(ah[dc].s, bl.s, acc[jt], 0, 0, 0);
        acc[jt] = __builtin_amdgcn_mfma_f32_16x16x32_bf16(al[dc].s, bh.s, acc[jt], 0, 0, 0);
      }
    }
  }

  __syncthreads();
  #pragma unroll
  for (int jt = 0; jt < 4; ++jt) {
    const int n = jt * 16 + lr;
    const float bi = bias[n0 + n];
    #pragma unroll
    for (int r = 0; r < 4; ++r) {
      const float v = acc[jt][r] + bi;
      const int row = wv * 16 + lg * 4 + r;
      unsigned short hi = f32_to_bf16(v);
      BsHi[row][n] = hi;
      if (z == 0) BsLo[row][n] = f32_to_bf16(v - bf16_to_f32(hi));
    }
  }
  __syncthreads();
  if (z == 2) {
    const int b2 = m0 >> 11, s0 = m0 & 2047, hh = n0 >> 6;
    const int d = tid >> 2, sc = (tid & 3) * 16;
    #pragma unroll
    for (int e = 0; e < 16; ++e)
      Vt[((size_t)(b2 * HEADS + hh) * DK + d) * SEQ + s0 + sc + e] =
          BsHi[sc + e][d];
  } else {
    unsigned short* Yhi = (z == 0) ? Qhi : Khi;
    #pragma unroll
    for (int p = 0; p < 2; ++p) {
      const int row = (tid >> 3) + p * 32;
      const int ch = (tid & 7) * 8;
      const size_t o = (size_t)(m0 + row) * DMODEL + n0 + ch;
      *(uint4*)&Yhi[o] = *(uint4*)&BsHi[row][ch];
      if (z == 0) *(uint4*)&Qlo[o] = *(uint4*)&BsLo[row][ch];
    }
  }
}

// ---------------------------------------------------------------------------
// Output projection: X = ctx bf16, Y = out f32.
// ---------------------------------------------------------------------------
__global__ __launch_bounds__(256) void proj_out_kernel(
    const unsigned short* __restrict__ X16, const unsigned short* __restrict__ WtHi,
    const unsigned short* __restrict__ WtLo, const float* __restrict__ bias,
    float* __restrict__ Yf) {
  __shared__ unsigned short BsHi[64][72];
  __shared__ unsigned short BsLo[64][72];
  const int tid = threadIdx.x, wv = tid >> 6, lane = tid & 63;
  const int lr = lane & 15, lg = lane >> 4;
  const int m0 = blockIdx.x * 64;
  const int mw = m0 + wv * 16;
  const int n0 = blockIdx.y * 64;

  f32x4 acc[4] = {};
  for (int k0 = 0; k0 < 512; k0 += 64) {
    FragU ah[2];
    #pragma unroll
    for (int dc = 0; dc < 2; ++dc) {
      const size_t xi = (size_t)(mw + lr) * DMODEL + k0 + dc * 32 + lg * 8;
      ah[dc].u = *(const uint4*)&X16[xi];
    }
    __syncthreads();
    #pragma unroll
    for (int e = 0; e < 2; ++e) {
      const int rr = (tid >> 3) + e * 32;
      const int cc = (tid & 7) * 8;
      *(uint4*)&BsHi[rr][cc] =
          *(const uint4*)&WtHi[(size_t)(n0 + rr) * DMODEL + k0 + cc];
      *(uint4*)&BsLo[rr][cc] =
          *(const uint4*)&WtLo[(size_t)(n0 + rr) * DMODEL + k0 + cc];
    }
    __syncthreads();
    #pragma unroll
    for (int jt = 0; jt < 4; ++jt) {
      #pragma unroll
      for (int dc = 0; dc < 2; ++dc) {
        FragU bh, bl;
        bh.u = *(const uint4*)&BsHi[jt * 16 + lr][dc * 32 + lg * 8];
        bl.u = *(const uint4*)&BsLo[jt * 16 + lr][dc * 32 + lg * 8];
        acc[jt] = __builtin_amdgcn_mfma_f32_16x16x32_bf16(ah[dc].s, bh.s, acc[jt], 0, 0, 0);
        acc[jt] = __builtin_amdgcn_mfma_f32_16x16x32_bf16(ah[dc].s, bl.s, acc[jt], 0, 0, 0);
      }
    }
  }
  #pragma unroll
  for (int jt = 0; jt < 4; ++jt) {
    const int n = n0 + jt * 16 + lr;
    const float bi = bias[n];
    #pragma unroll
    for (int r = 0; r < 4; ++r)
      Yf[(size_t)(mw + lg * 4 + r) * DMODEL + n] = acc[jt][r] + bi;
  }
}

// ---------------------------------------------------------------------------
// ONE-PASS fused attention v7: 512 thr / 8 waves, 16 q-rows, 256 cols/wave,
// EXPLICIT PING-PONG PIPELINING: K in 4 batches of 4 t-steps with batch g+1
// issued before computing batch g; V chunk 0 hoisted above the l-reduce
// barrier, chunk c+1 issued during chunk c. launch_bounds(512,2) -> VGPR cap
// 256 so both buffers stay resident (R22's 64-VGPR alloc couldn't).
// Spill detector: if VGPR<=64 or WRITE>>266MB, experiment corrupted.
// No-max softmax; e as f16 pairs; pbuf stride 76; 8-way ctx tree-reduce.
// MFMA maps (verified): A[lr][lg*8+j]; B[lg*8+j][lr]; D[lg*4+r][lr].
// ---------------------------------------------------------------------------
__global__ __launch_bounds__(512, 2) void attn_fused_kernel(
    const unsigned short* __restrict__ Qhi, const unsigned short* __restrict__ Qlo,
    const unsigned short* __restrict__ Khi, const unsigned int* __restrict__ bits,
    const unsigned short* __restrict__ Vt, float* __restrict__ attn,
    unsigned short* __restrict__ ctx16) {
  __shared__ unsigned short pbuf[8][16 * 76];  // 19456 B (also ctx reduce buf)
  __shared__ float smred[8][16];               // 512 B (l partials)
  const int id = blockIdx.x;                   // 2048 blocks, XCD-swizzled
  const int xcd = id & 7, slot = id >> 3;      // slot 0..255
  const int bh = xcd + 8 * (slot & 1);
  const int qt = slot >> 1;                    // 0..127
  const int b = bh >> 3, h = bh & 7;
  const int tid = threadIdx.x, wv = tid >> 6, lane = tid & 63;
  const int lr = lane & 15, lg = lane >> 4;
  const int q0 = qt * 16;
  const int kw = wv * 256;  // wave's k-column base (8 waves x 256 = 2048)

  // Q frags (A layout: q-row = q0 + lr), hi+lo
  FragU qh[2], ql[2];
  #pragma unroll
  for (int dc = 0; dc < 2; ++dc) {
    const size_t qi = (size_t)(b * SEQ + q0 + lr) * DMODEL + h * DK + dc * 32 + lg * 8;
    qh[dc].u = *(const uint4*)&Qhi[qi];
    ql[dc].u = *(const uint4*)&Qlo[qi];
  }
  // mask words: 256 cols = 8 words per row -> two uint4 per row
  uint4 mw8[4][2];
  #pragma unroll
  for (int r = 0; r < 4; ++r) {
    const size_t base = ((size_t)b * SEQ + q0 + lg * 4 + r) * 64 + (kw >> 5);
    mw8[r][0] = *(const uint4*)&bits[base];
    mw8[r][1] = *(const uint4*)&bits[base + 4];
  }

  const size_t krow_base = (size_t)(b * SEQ + kw + lr) * DMODEL + h * DK + lg * 8;
  // one t-step advances the row by 16 -> 16*DMODEL elements

  // ---- phase 1: 4 batches of 4 t-steps, ping-pong prefetch ----
  const float C = 0.125f * 1.44269504089f;  // fold scale into exp2
  PkU epk[16][2];
  float ls[4] = {0.f, 0.f, 0.f, 0.f};
  FragU khA[4][2], khB[4][2];
  #pragma unroll
  for (int tt = 0; tt < 4; ++tt)
    #pragma unroll
    for (int dc = 0; dc < 2; ++dc)
      khA[tt][dc].u =
          *(const uint4*)&Khi[krow_base + (size_t)tt * 16 * DMODEL + dc * 32];

  #pragma unroll
  for (int g = 0; g < 4; ++g) {
    // prefetch batch g+1 into the other buffer
    if (g < 3) {
      #pragma unroll
      for (int tt = 0; tt < 4; ++tt)
        #pragma unroll
        for (int dc = 0; dc < 2; ++dc) {
          const int t = (g + 1) * 4 + tt;
          ((g & 1) ? khA : khB)[tt][dc].u =
              *(const uint4*)&Khi[krow_base + (size_t)t * 16 * DMODEL + dc * 32];
        }
    }
    FragU(*cur)[2] = (g & 1) ? khB : khA;
    #pragma unroll
    for (int tt = 0; tt < 4; ++tt) {
      const int t = g * 4 + tt;
      f32x4 sa = {};
      #pragma unroll
      for (int dc = 0; dc < 2; ++dc) {
        sa = __builtin_amdgcn_mfma_f32_16x16x32_bf16(qh[dc].s, cur[tt][dc].s, sa, 0, 0, 0);
        sa = __builtin_amdgcn_mfma_f32_16x16x32_bf16(ql[dc].s, cur[tt][dc].s, sa, 0, 0, 0);
      }
      const int wi = t >> 1;  // 0..7, compile-time
      float ev[4];
      #pragma unroll
      for (int r = 0; r < 4; ++r) {
        const uint4 m4 = mw8[r][wi >> 2];
        const unsigned int w =
            (wi & 3) == 0 ? m4.x : (wi & 3) == 1 ? m4.y : (wi & 3) == 2 ? m4.z : m4.w;
        const bool keep = (w >> (((t & 1) << 4) + lr)) & 1;
        const float e = keep ? exp2f(sa[r] * C) : 0.0f;
        ev[r] = e;
        ls[r] += e;
      }
      epk[t][0].h = __builtin_amdgcn_cvt_pkrtz(ev[0], ev[1]);
      epk[t][1].h = __builtin_amdgcn_cvt_pkrtz(ev[2], ev[3]);
    }
  }

  // ---- l: shfl reduce over the 16-lane lr group, then cross-wave via LDS ----
  #pragma unroll
  for (int r = 0; r < 4; ++r) {
    #pragma unroll
    for (int off = 1; off < 16; off <<= 1) ls[r] += __shfl_xor(ls[r], off);
    if (lr == 0) smred[wv][lg * 4 + r] = ls[r];
  }
  // V chunk 0 prefetch (independent of il) overlaps the barrier + il compute
  const size_t vrow_base = (size_t)bh * DK * SEQ + kw + lg * 8;
  FragU vvA[2][4], vvB[2][4];
  #pragma unroll
  for (int dc2 = 0; dc2 < 2; ++dc2)
    #pragma unroll
    for (int dt = 0; dt < 4; ++dt)
      vvA[dc2][dt].u = *(const uint4*)&Vt[vrow_base + (size_t)(dt * 16 + lr) * SEQ +
                                          dc2 * 32];
  __syncthreads();
  float il[4];
  #pragma unroll
  for (int r = 0; r < 4; ++r) {
    float l = 0.f;
    #pragma unroll
    for (int w2 = 0; w2 < 8; ++w2) l += smred[w2][lg * 4 + r];
    il[r] = 1.0f / l;
  }

  // ---- phase 2: per 64-col chunk, ping-pong V prefetch ----
  unsigned short* pb = pbuf[wv];
  f32x4 acc[4] = {};
  #pragma unroll
  for (int c = 0; c < 4; ++c) {
    if (c < 3) {
      #pragma unroll
      for (int dc2 = 0; dc2 < 2; ++dc2)
        #pragma unroll
        for (int dt = 0; dt < 4; ++dt)
          ((c & 1) ? vvA : vvB)[dc2][dt].u =
              *(const uint4*)&Vt[vrow_base + (size_t)(dt * 16 + lr) * SEQ +
                                 (c + 1) * 64 + dc2 * 32];
    }
    FragU(*vcur)[4] = (c & 1) ? vvB : vvA;
    #pragma unroll
    for (int tt = 0; tt < 4; ++tt) {
      const int t = c * 4 + tt;
      float pv4[4];
      pv4[0] = (float)epk[t][0].h.x * il[0];
      pv4[1] = (float)epk[t][0].h.y * il[1];
      pv4[2] = (float)epk[t][1].h.x * il[2];
      pv4[3] = (float)epk[t][1].h.y * il[3];
      #pragma unroll
      for (int r = 0; r < 4; ++r) {
        const int q = q0 + lg * 4 + r;
        attn[((size_t)bh * SEQ + q) * SEQ + kw + t * 16 + lr] = pv4[r];
        pb[(lg * 4 + r) * 76 + tt * 16 + lr] = f32_to_bf16(pv4[r]);
      }
    }
    #pragma unroll
    for (int dc2 = 0; dc2 < 2; ++dc2) {
      FragU pa;
      pa.u = *(const uint4*)&pb[lr * 76 + dc2 * 32 + lg * 8];
      #pragma unroll
      for (int dt = 0; dt < 4; ++dt)
        acc[dt] = __builtin_amdgcn_mfma_f32_16x16x32_bf16(pa.s, vcur[dc2][dt].s, acc[dt], 0, 0, 0);
    }
  }

  // ---- 8-way ctx tree-reduce through pbuf (16 KB max in flight) ----
  float* red = (float*)&pbuf[0][0];
  #pragma unroll 1
  for (int ofs = 4; ofs > 0; ofs >>= 1) {
    __syncthreads();
    if (wv >= ofs && wv < 2 * ofs) {
      float* dst = red + (size_t)(wv - ofs) * 1024;
      #pragma unroll
      for (int dt = 0; dt < 4; ++dt) *(f32x4*)&dst[dt * 256 + lane * 4] = acc[dt];
    }
    __syncthreads();
    if (wv < ofs) {
      const float* src = red + (size_t)wv * 1024;
      #pragma unroll
      for (int dt = 0; dt < 4; ++dt) acc[dt] += *(const f32x4*)&src[dt * 256 + lane * 4];
    }
  }
  if (wv == 0) {
    #pragma unroll
    for (int dt = 0; dt < 4; ++dt)
      #pragma unroll
      for (int r = 0; r < 4; ++r) {
        const int q = q0 + lg * 4 + r;
        ctx16[(size_t)(b * SEQ + q) * DMODEL + h * DK + dt * 16 + lr] =
            f32_to_bf16(acc[dt][r]);
      }
  }
}

// ---------------------------------------------------------------------------
extern "C" void kernel_launch(void* const* d_in, const int* in_sizes, int n_in,
                              void* d_out, int out_size, void* d_ws,
                              size_t ws_size, hipStream_t stream) {
  const float* q = (const float*)d_in[0];
  const float* k = (const float*)d_in[1];
  const float* v = (const float*)d_in[2];
  const int* mask = (const int*)d_in[3];
  const float* Wq = (const float*)d_in[4];
  const float* bq = (const float*)d_in[5];
  const float* Wk = (const float*)d_in[6];
  const float* bk = (const float*)d_in[7];
  const float* Wv = (const float*)d_in[8];
  const float* bv = (const float*)d_in[9];
  const float* Wo = (const float*)d_in[10];
  const float* bo = (const float*)d_in[11];

  float* out = (float*)d_out;
  float* attn = out + (size_t)BATCH * SEQ * DMODEL;

  char* w = (char*)d_ws;
  const size_t MB = 1u << 20;
  unsigned short* Qhi = (unsigned short*)(w + 0 * MB);     // flat [4096][512] bf16, 4MB
  unsigned short* Qlo = (unsigned short*)(w + 4 * MB);     // 4MB
  unsigned short* Khi = (unsigned short*)(w + 8 * MB);     // 4MB, single bf16
  unsigned short* WtHi4 = (unsigned short*)(w + 12 * MB);  // 4 x 512KB = 2MB
  unsigned short* WtLo4 = (unsigned short*)(w + 14 * MB);  // 2MB
  unsigned short* ctx16 = (unsigned short*)(w + 16 * MB);  // 4MB
  unsigned short* Vt = (unsigned short*)(w + 20 * MB);     // 4MB [bh][d][s]
  unsigned int* bits = (unsigned int*)(w + 24 * MB);       // 1 MB

  const size_t WSTRIDE = (size_t)DMODEL * DMODEL;  // 262144 elements per pair

  dim3 blk(256);
  wsplit4_kernel<<<dim3(8, 8, 4), blk, 0, stream>>>(Wq, Wk, Wv, Wo, WtHi4, WtLo4);

  fused_front_kernel<<<dim3(5632), blk, 0, stream>>>(
      q, k, v, WtHi4, WtLo4, bq, bk, bv, Qhi, Qlo, Khi, Vt, mask, bits);

  attn_fused_kernel<<<dim3(2048), dim3(512), 0, stream>>>(Qhi, Qlo, Khi, bits,
                                                          Vt, attn, ctx16);

  proj_out_kernel<<<dim3(64, 8), blk, 0, stream>>>(
      ctx16, WtHi4 + 3 * WSTRIDE, WtLo4 + 3 * WSTRIDE, bo, out);
}

// Round 24
// 208.703 us; speedup vs baseline: 1.0759x; 1.0759x over previous
//
#include <hip/hip_runtime.h>
#include <math.h>

#define HEADS 8
#define DK 64
#define DMODEL 512
#define BATCH 2
#define SEQ 2048
#define BH (BATCH * HEADS)

using f32x4 = __attribute__((ext_vector_type(4))) float;
using s16x8 = __attribute__((ext_vector_type(8))) short;
using fp16x2 = __attribute__((ext_vector_type(2))) __fp16;  // cvt_pkrtz's type

union FragU {
  uint4 u;
  s16x8 s;
  unsigned short us[8];
};
union PkU {
  fp16x2 h;
  unsigned int u;
};

__device__ __forceinline__ unsigned short f32_to_bf16(float f) {
  unsigned int u = __float_as_uint(f);
  u += 0x7fffu + ((u >> 16) & 1u);
  return (unsigned short)(u >> 16);
}
__device__ __forceinline__ float bf16_to_f32(unsigned short h) {
  return __uint_as_float(((unsigned int)h) << 16);
}

// ---------------------------------------------------------------------------
// ALL FOUR W[512][512] f32 -> Wt hi/lo bf16 [n][k] in one launch.
// ---------------------------------------------------------------------------
__global__ __launch_bounds__(256) void wsplit4_kernel(
    const float* __restrict__ W0, const float* __restrict__ W1,
    const float* __restrict__ W2, const float* __restrict__ W3,
    unsigned short* __restrict__ WtHi4, unsigned short* __restrict__ WtLo4) {
  __shared__ float t[64][65];
  const int z = blockIdx.z;
  const float* W = (z == 0) ? W0 : (z == 1) ? W1 : (z == 2) ? W2 : W3;
  unsigned short* WtHi = WtHi4 + (size_t)z * (DMODEL * DMODEL);
  unsigned short* WtLo = WtLo4 + (size_t)z * (DMODEL * DMODEL);
  const int k0 = blockIdx.x * 64, n0 = blockIdx.y * 64;
  const int tid = threadIdx.x;
  const int r = tid >> 2, c = (tid & 3) * 16;
  #pragma unroll
  for (int e = 0; e < 4; ++e) {
    f32x4 v = *(const f32x4*)&W[(size_t)(k0 + r) * DMODEL + n0 + c + e * 4];
    #pragma unroll
    for (int j = 0; j < 4; ++j) t[r][c + e * 4 + j] = v[j];
  }
  __syncthreads();
  const int rn = tid >> 2, ck = (tid & 3) * 16;
  #pragma unroll
  for (int half = 0; half < 2; ++half) {
    FragU hi, lo;
    #pragma unroll
    for (int e = 0; e < 8; ++e) {
      float x = t[ck + half * 8 + e][rn];
      unsigned short h = f32_to_bf16(x);
      hi.us[e] = h;
      lo.us[e] = f32_to_bf16(x - bf16_to_f32(h));
    }
    const size_t o = (size_t)(n0 + rn) * DMODEL + k0 + ck + half * 8;
    *(uint4*)&WtHi[o] = hi.u;
    *(uint4*)&WtLo[o] = lo.u;
  }
}

// ---------------------------------------------------------------------------
// FUSED FRONT: Q/K/V projections (blocks 0..1535) + mask byte-pack (rest).
// ---------------------------------------------------------------------------
__global__ __launch_bounds__(256) void fused_front_kernel(
    const float* __restrict__ Xq, const float* __restrict__ Xk,
    const float* __restrict__ Xv, const unsigned short* __restrict__ WtHi4,
    const unsigned short* __restrict__ WtLo4, const float* __restrict__ bq,
    const float* __restrict__ bk, const float* __restrict__ bv,
    unsigned short* __restrict__ Qhi, unsigned short* __restrict__ Qlo,
    unsigned short* __restrict__ Khi, unsigned short* __restrict__ Vt,
    const int* __restrict__ mask, unsigned int* __restrict__ bits) {
  __shared__ unsigned short BsHi[64][72];
  __shared__ unsigned short BsLo[64][72];
  const int id = blockIdx.x;
  const int tid = threadIdx.x;

  if (id >= 1536) {
    const int row = id - 1536;  // 0..4095
    const int4* mrow = (const int4*)&mask[(size_t)row * SEQ + tid * 8];
    const int4 a = mrow[0];
    const int4 bb = mrow[1];
    unsigned int byte = 0;
    byte |= (a.x != 0) ? 1u : 0u;
    byte |= (a.y != 0) ? 2u : 0u;
    byte |= (a.z != 0) ? 4u : 0u;
    byte |= (a.w != 0) ? 8u : 0u;
    byte |= (bb.x != 0) ? 16u : 0u;
    byte |= (bb.y != 0) ? 32u : 0u;
    byte |= (bb.z != 0) ? 64u : 0u;
    byte |= (bb.w != 0) ? 128u : 0u;
    ((unsigned char*)bits)[(size_t)row * 256 + tid] = (unsigned char)byte;
    return;
  }

  const int z = id >> 9;
  const int rem = id & 511;
  const int m0 = (rem & 63) * 64;
  const int n0 = (rem >> 6) * 64;
  const float* X = (z == 0) ? Xq : (z == 1) ? Xk : Xv;
  const float* bias = (z == 0) ? bq : (z == 1) ? bk : bv;
  const unsigned short* WtHi = WtHi4 + (size_t)z * (DMODEL * DMODEL);
  const unsigned short* WtLo = WtLo4 + (size_t)z * (DMODEL * DMODEL);

  const int wv = tid >> 6, lane = tid & 63;
  const int lr = lane & 15, lg = lane >> 4;
  const int mw = m0 + wv * 16;

  f32x4 acc[4] = {};
  for (int k0 = 0; k0 < 512; k0 += 64) {
    FragU ah[2], al[2];
    #pragma unroll
    for (int dc = 0; dc < 2; ++dc) {
      const size_t xi = (size_t)(mw + lr) * DMODEL + k0 + dc * 32 + lg * 8;
      f32x4 x0 = *(const f32x4*)&X[xi];
      f32x4 x1 = *(const f32x4*)&X[xi + 4];
      #pragma unroll
      for (int t = 0; t < 4; ++t) {
        unsigned short h0 = f32_to_bf16(x0[t]);
        unsigned short h1 = f32_to_bf16(x1[t]);
        ah[dc].us[t] = h0;
        ah[dc].us[4 + t] = h1;
        al[dc].us[t] = f32_to_bf16(x0[t] - bf16_to_f32(h0));
        al[dc].us[4 + t] = f32_to_bf16(x1[t] - bf16_to_f32(h1));
      }
    }
    __syncthreads();
    #pragma unroll
    for (int e = 0; e < 2; ++e) {
      const int rr = (tid >> 3) + e * 32;
      const int cc = (tid & 7) * 8;
      *(uint4*)&BsHi[rr][cc] =
          *(const uint4*)&WtHi[(size_t)(n0 + rr) * DMODEL + k0 + cc];
      *(uint4*)&BsLo[rr][cc] =
          *(const uint4*)&WtLo[(size_t)(n0 + rr) * DMODEL + k0 + cc];
    }
    __syncthreads();
    #pragma unroll
    for (int jt = 0; jt < 4; ++jt) {
      #pragma unroll
      for (int dc = 0; dc < 2; ++dc) {
        FragU bh, bl;
        bh.u = *(const uint4*)&BsHi[jt * 16 + lr][dc * 32 + lg * 8];
        bl.u = *(const uint4*)&BsLo[jt * 16 + lr][dc * 32 + lg * 8];
        acc[jt] = __builtin_amdgcn_mfma_f32_16x16x32_bf16(ah[dc].s, bh.s, acc[jt], 0, 0, 0);
        acc[jt] = __builtin_amdgcn_mfma_f32_16x16x32_bf16(ah[dc].s, bl.s, acc[jt], 0, 0, 0);
        acc[jt] = __builtin_amdgcn_mfma_f32_16x16x32_bf16(al[dc].s, bh.s, acc[jt], 0, 0, 0);
      }
    }
  }

  __syncthreads();
  #pragma unroll
  for (int jt = 0; jt < 4; ++jt) {
    const int n = jt * 16 + lr;
    const float bi = bias[n0 + n];
    #pragma unroll
    for (int r = 0; r < 4; ++r) {
      const float v = acc[jt][r] + bi;
      const int row = wv * 16 + lg * 4 + r;
      unsigned short hi = f32_to_bf16(v);
      BsHi[row][n] = hi;
      if (z == 0) BsLo[row][n] = f32_to_bf16(v - bf16_to_f32(hi));
    }
  }
  __syncthreads();
  if (z == 2) {
    const int b2 = m0 >> 11, s0 = m0 & 2047, hh = n0 >> 6;
    const int d = tid >> 2, sc = (tid & 3) * 16;
    #pragma unroll
    for (int e = 0; e < 16; ++e)
      Vt[((size_t)(b2 * HEADS + hh) * DK + d) * SEQ + s0 + sc + e] =
          BsHi[sc + e][d];
  } else {
    unsigned short* Yhi = (z == 0) ? Qhi : Khi;
    #pragma unroll
    for (int p = 0; p < 2; ++p) {
      const int row = (tid >> 3) + p * 32;
      const int ch = (tid & 7) * 8;
      const size_t o = (size_t)(m0 + row) * DMODEL + n0 + ch;
      *(uint4*)&Yhi[o] = *(uint4*)&BsHi[row][ch];
      if (z == 0) *(uint4*)&Qlo[o] = *(uint4*)&BsLo[row][ch];
    }
  }
}

// ---------------------------------------------------------------------------
// Output projection: X = ctx bf16, Y = out f32.
// ---------------------------------------------------------------------------
__global__ __launch_bounds__(256) void proj_out_kernel(
    const unsigned short* __restrict__ X16, const unsigned short* __restrict__ WtHi,
    const unsigned short* __restrict__ WtLo, const float* __restrict__ bias,
    float* __restrict__ Yf) {
  __shared__ unsigned short BsHi[64][72];
  __shared__ unsigned short BsLo[64][72];
  const int tid = threadIdx.x, wv = tid >> 6, lane = tid & 63;
  const int lr = lane & 15, lg = lane >> 4;
  const int m0 = blockIdx.x * 64;
  const int mw = m0 + wv * 16;
  const int n0 = blockIdx.y * 64;

  f32x4 acc[4] = {};
  for (int k0 = 0; k0 < 512; k0 += 64) {
    FragU ah[2];
    #pragma unroll
    for (int dc = 0; dc < 2; ++dc) {
      const size_t xi = (size_t)(mw + lr) * DMODEL + k0 + dc * 32 + lg * 8;
      ah[dc].u = *(const uint4*)&X16[xi];
    }
    __syncthreads();
    #pragma unroll
    for (int e = 0; e < 2; ++e) {
      const int rr = (tid >> 3) + e * 32;
      const int cc = (tid & 7) * 8;
      *(uint4*)&BsHi[rr][cc] =
          *(const uint4*)&WtHi[(size_t)(n0 + rr) * DMODEL + k0 + cc];
      *(uint4*)&BsLo[rr][cc] =
          *(const uint4*)&WtLo[(size_t)(n0 + rr) * DMODEL + k0 + cc];
    }
    __syncthreads();
    #pragma unroll
    for (int jt = 0; jt < 4; ++jt) {
      #pragma unroll
      for (int dc = 0; dc < 2; ++dc) {
        FragU bh, bl;
        bh.u = *(const uint4*)&BsHi[jt * 16 + lr][dc * 32 + lg * 8];
        bl.u = *(const uint4*)&BsLo[jt * 16 + lr][dc * 32 + lg * 8];
        acc[jt] = __builtin_amdgcn_mfma_f32_16x16x32_bf16(ah[dc].s, bh.s, acc[jt], 0, 0, 0);
        acc[jt] = __builtin_amdgcn_mfma_f32_16x16x32_bf16(ah[dc].s, bl.s, acc[jt], 0, 0, 0);
      }
    }
  }
  #pragma unroll
  for (int jt = 0; jt < 4; ++jt) {
    const int n = n0 + jt * 16 + lr;
    const float bi = bias[n];
    #pragma unroll
    for (int r = 0; r < 4; ++r)
      Yf[(size_t)(mw + lg * 4 + r) * DMODEL + n] = acc[jt][r] + bi;
  }
}

// ---------------------------------------------------------------------------
// ONE-PASS fused attention v6 (EXACT R22 build — best: 158us, VGPR 64, no
// spill): 512 thr / 8 waves, 16 q-rows, 256 cols/wave, K in two flat batches
// of 16 uint4 (compiler schedules the pipelining — manual ping-pong (R23),
// wave-private (R5), and 2-qset (R14-16) variants all lost to it), V frags
// issued at the top of each 64-col chunk.
// No-max softmax; e as f16 pairs; pbuf stride 76; 8-way ctx tree-reduce.
// MFMA maps (verified): A[lr][lg*8+j]; B[lg*8+j][lr]; D[lg*4+r][lr].
// ---------------------------------------------------------------------------
__global__ __launch_bounds__(512) void attn_fused_kernel(
    const unsigned short* __restrict__ Qhi, const unsigned short* __restrict__ Qlo,
    const unsigned short* __restrict__ Khi, const unsigned int* __restrict__ bits,
    const unsigned short* __restrict__ Vt, float* __restrict__ attn,
    unsigned short* __restrict__ ctx16) {
  __shared__ unsigned short pbuf[8][16 * 76];  // 19456 B (also ctx reduce buf)
  __shared__ float smred[8][16];               // 512 B (l partials)
  const int id = blockIdx.x;                   // 2048 blocks, XCD-swizzled
  const int xcd = id & 7, slot = id >> 3;      // slot 0..255
  const int bh = xcd + 8 * (slot & 1);
  const int qt = slot >> 1;                    // 0..127
  const int b = bh >> 3, h = bh & 7;
  const int tid = threadIdx.x, wv = tid >> 6, lane = tid & 63;
  const int lr = lane & 15, lg = lane >> 4;
  const int q0 = qt * 16;
  const int kw = wv * 256;  // wave's k-column base (8 waves x 256 = 2048)

  // Q frags (A layout: q-row = q0 + lr), hi+lo
  FragU qh[2], ql[2];
  #pragma unroll
  for (int dc = 0; dc < 2; ++dc) {
    const size_t qi = (size_t)(b * SEQ + q0 + lr) * DMODEL + h * DK + dc * 32 + lg * 8;
    qh[dc].u = *(const uint4*)&Qhi[qi];
    ql[dc].u = *(const uint4*)&Qlo[qi];
  }
  // mask words: 256 cols = 8 words per row -> two uint4 per row
  uint4 mw8[4][2];
  #pragma unroll
  for (int r = 0; r < 4; ++r) {
    const size_t base = ((size_t)b * SEQ + q0 + lg * 4 + r) * 64 + (kw >> 5);
    mw8[r][0] = *(const uint4*)&bits[base];
    mw8[r][1] = *(const uint4*)&bits[base + 4];
  }

  // ---- phase 1: 2 batches of 8 t-steps; K prefetched per batch ----
  const float C = 0.125f * 1.44269504089f;  // fold scale into exp2
  PkU epk[16][2];
  float ls[4] = {0.f, 0.f, 0.f, 0.f};
  #pragma unroll
  for (int g = 0; g < 2; ++g) {
    FragU kh[8][2];  // 16 uint4 batch; compiler pipelines
    #pragma unroll
    for (int tt = 0; tt < 8; ++tt) {
      const int t = g * 8 + tt;
      #pragma unroll
      for (int dc = 0; dc < 2; ++dc) {
        const size_t kidx =
            (size_t)(b * SEQ + kw + t * 16 + lr) * DMODEL + h * DK + dc * 32 + lg * 8;
        kh[tt][dc].u = *(const uint4*)&Khi[kidx];
      }
    }
    #pragma unroll
    for (int tt = 0; tt < 8; ++tt) {
      const int t = g * 8 + tt;
      f32x4 sa = {};
      #pragma unroll
      for (int dc = 0; dc < 2; ++dc) {
        sa = __builtin_amdgcn_mfma_f32_16x16x32_bf16(qh[dc].s, kh[tt][dc].s, sa, 0, 0, 0);
        sa = __builtin_amdgcn_mfma_f32_16x16x32_bf16(ql[dc].s, kh[tt][dc].s, sa, 0, 0, 0);
      }
      const int wi = t >> 1;  // 0..7, compile-time
      float ev[4];
      #pragma unroll
      for (int r = 0; r < 4; ++r) {
        const uint4 m4 = mw8[r][wi >> 2];
        const unsigned int w =
            (wi & 3) == 0 ? m4.x : (wi & 3) == 1 ? m4.y : (wi & 3) == 2 ? m4.z : m4.w;
        const bool keep = (w >> (((t & 1) << 4) + lr)) & 1;
        const float e = keep ? exp2f(sa[r] * C) : 0.0f;
        ev[r] = e;
        ls[r] += e;
      }
      epk[t][0].h = __builtin_amdgcn_cvt_pkrtz(ev[0], ev[1]);
      epk[t][1].h = __builtin_amdgcn_cvt_pkrtz(ev[2], ev[3]);
    }
  }

  // ---- l: shfl reduce over the 16-lane lr group, then cross-wave via LDS ----
  #pragma unroll
  for (int r = 0; r < 4; ++r) {
    #pragma unroll
    for (int off = 1; off < 16; off <<= 1) ls[r] += __shfl_xor(ls[r], off);
    if (lr == 0) smred[wv][lg * 4 + r] = ls[r];
  }
  __syncthreads();
  float il[4];
  #pragma unroll
  for (int r = 0; r < 4; ++r) {
    float l = 0.f;
    #pragma unroll
    for (int w2 = 0; w2 < 8; ++w2) l += smred[w2][lg * 4 + r];
    il[r] = 1.0f / l;
  }

  // ---- phase 2: per 64-col chunk: V prefetch -> p/attn/pbuf -> PV MFMA ----
  unsigned short* pb = pbuf[wv];
  f32x4 acc[4] = {};
  #pragma unroll
  for (int c = 0; c < 4; ++c) {
    // issue all 8 V loads for this chunk first (latency hides under p work)
    FragU vv[2][4];
    #pragma unroll
    for (int dc2 = 0; dc2 < 2; ++dc2)
      #pragma unroll
      for (int dt = 0; dt < 4; ++dt)
        vv[dc2][dt].u = *(const uint4*)&Vt[((size_t)bh * DK + dt * 16 + lr) * SEQ +
                                           kw + c * 64 + dc2 * 32 + lg * 8];
    #pragma unroll
    for (int tt = 0; tt < 4; ++tt) {
      const int t = c * 4 + tt;
      float pv4[4];
      pv4[0] = (float)epk[t][0].h.x * il[0];
      pv4[1] = (float)epk[t][0].h.y * il[1];
      pv4[2] = (float)epk[t][1].h.x * il[2];
      pv4[3] = (float)epk[t][1].h.y * il[3];
      #pragma unroll
      for (int r = 0; r < 4; ++r) {
        const int q = q0 + lg * 4 + r;
        attn[((size_t)bh * SEQ + q) * SEQ + kw + t * 16 + lr] = pv4[r];
        pb[(lg * 4 + r) * 76 + tt * 16 + lr] = f32_to_bf16(pv4[r]);
      }
    }
    #pragma unroll
    for (int dc2 = 0; dc2 < 2; ++dc2) {
      FragU pa;
      pa.u = *(const uint4*)&pb[lr * 76 + dc2 * 32 + lg * 8];
      #pragma unroll
      for (int dt = 0; dt < 4; ++dt)
        acc[dt] = __builtin_amdgcn_mfma_f32_16x16x32_bf16(pa.s, vv[dc2][dt].s, acc[dt], 0, 0, 0);
    }
  }

  // ---- 8-way ctx tree-reduce through pbuf (16 KB max in flight) ----
  float* red = (float*)&pbuf[0][0];
  #pragma unroll 1
  for (int ofs = 4; ofs > 0; ofs >>= 1) {
    __syncthreads();
    if (wv >= ofs && wv < 2 * ofs) {
      float* dst = red + (size_t)(wv - ofs) * 1024;
      #pragma unroll
      for (int dt = 0; dt < 4; ++dt) *(f32x4*)&dst[dt * 256 + lane * 4] = acc[dt];
    }
    __syncthreads();
    if (wv < ofs) {
      const float* src = red + (size_t)wv * 1024;
      #pragma unroll
      for (int dt = 0; dt < 4; ++dt) acc[dt] += *(const f32x4*)&src[dt * 256 + lane * 4];
    }
  }
  if (wv == 0) {
    #pragma unroll
    for (int dt = 0; dt < 4; ++dt)
      #pragma unroll
      for (int r = 0; r < 4; ++r) {
        const int q = q0 + lg * 4 + r;
        ctx16[(size_t)(b * SEQ + q) * DMODEL + h * DK + dt * 16 + lr] =
            f32_to_bf16(acc[dt][r]);
      }
  }
}

// ---------------------------------------------------------------------------
extern "C" void kernel_launch(void* const* d_in, const int* in_sizes, int n_in,
                              void* d_out, int out_size, void* d_ws,
                              size_t ws_size, hipStream_t stream) {
  const float* q = (const float*)d_in[0];
  const float* k = (const float*)d_in[1];
  const float* v = (const float*)d_in[2];
  const int* mask = (const int*)d_in[3];
  const float* Wq = (const float*)d_in[4];
  const float* bq = (const float*)d_in[5];
  const float* Wk = (const float*)d_in[6];
  const float* bk = (const float*)d_in[7];
  const float* Wv = (const float*)d_in[8];
  const float* bv = (const float*)d_in[9];
  const float* Wo = (const float*)d_in[10];
  const float* bo = (const float*)d_in[11];

  float* out = (float*)d_out;
  float* attn = out + (size_t)BATCH * SEQ * DMODEL;

  char* w = (char*)d_ws;
  const size_t MB = 1u << 20;
  unsigned short* Qhi = (unsigned short*)(w + 0 * MB);     // flat [4096][512] bf16, 4MB
  unsigned short* Qlo = (unsigned short*)(w + 4 * MB);     // 4MB
  unsigned short* Khi = (unsigned short*)(w + 8 * MB);     // 4MB, single bf16
  unsigned short* WtHi4 = (unsigned short*)(w + 12 * MB);  // 4 x 512KB = 2MB
  unsigned short* WtLo4 = (unsigned short*)(w + 14 * MB);  // 2MB
  unsigned short* ctx16 = (unsigned short*)(w + 16 * MB);  // 4MB
  unsigned short* Vt = (unsigned short*)(w + 20 * MB);     // 4MB [bh][d][s]
  unsigned int* bits = (unsigned int*)(w + 24 * MB);       // 1 MB

  const size_t WSTRIDE = (size_t)DMODEL * DMODEL;  // 262144 elements per pair

  dim3 blk(256);
  wsplit4_kernel<<<dim3(8, 8, 4), blk, 0, stream>>>(Wq, Wk, Wv, Wo, WtHi4, WtLo4);

  fused_front_kernel<<<dim3(5632), blk, 0, stream>>>(
      q, k, v, WtHi4, WtLo4, bq, bk, bv, Qhi, Qlo, Khi, Vt, mask, bits);

  attn_fused_kernel<<<dim3(2048), dim3(512), 0, stream>>>(Qhi, Qlo, Khi, bits,
                                                          Vt, attn, ctx16);

  proj_out_kernel<<<dim3(64, 8), blk, 0, stream>>>(
      ctx16, WtHi4 + 3 * WSTRIDE, WtLo4 + 3 * WSTRIDE, bo, out);
}